// Round 7
// baseline (396.418 us; speedup 1.0000x reference)
//
#include <hip/hip_runtime.h>

typedef __attribute__((ext_vector_type(8))) short short8;
typedef __attribute__((ext_vector_type(16))) float f32x16;

#define MFMA(a, b, c) __builtin_amdgcn_mfma_f32_32x32x16_bf16((a), (b), (c), 0, 0, 0)

// packed f32 -> 2x bf16 (RNE), D[15:0]=bf16(a), D[31:16]=bf16(b)
__device__ __forceinline__ unsigned int cvt_pk_bf16(float a, float b) {
    unsigned int r;
    asm("v_cvt_pk_bf16_f32 %0, %1, %2" : "=v"(r) : "v"(a), "v"(b));
    return r;
}

// v_permlane32_swap_b32 a, b :  a' = {a[0:31], b[0:31]},  b' = {a[32:63], b[32:63]}
#define SWAP_HALVES(a, b) asm("v_permlane32_swap_b32 %0, %1" : "+v"(a), "+v"(b))

union FR { short8 v; unsigned int d[4]; };
union U4 { short8 v; uint4 u; };

// One 64x64 symmetric matrix, bf16 hi/lo, in MFMA A-fragment form.
// h[2*I+J][s] = A-frag of 32x32 block (I,J), K-step s. 64 VGPR total.
// B-operand of block [K][J] == A-form of block [J][K] (matrix symmetry).
struct Mat { short8 h[4][2]; short8 l[4][2]; };

// 1 wave = 1 matrix. No __syncthreads anywhere; LDS is a private per-wave
// staging buffer for the Y-update (register peak control only).
extern "C" __global__ void __launch_bounds__(256, 2)
isqrtm_kernel(const float* __restrict__ x, const int* __restrict__ iterN_p,
              float* __restrict__ out)
{
    __shared__ uint4 stg[4][4][4][64];   // [wave][dst-blk][frag][lane] = 64 KiB

    const int t = threadIdx.x;
    const int wv = t >> 6, lane = t & 63;
    const int m = lane & 31, h = lane >> 5;

    const int iterN = iterN_p[0];
    const size_t mat = (size_t)blockIdx.x * 4 + wv;
    const float* xg = x + mat * 4096;
    float* og = out + mat * 4096;

    // ---- trace (normA) ----
    float tv = xg[lane * 65];
    #pragma unroll
    for (int off = 32; off > 0; off >>= 1) tv += __shfl_down(tv, off);
    const float tr  = __shfl(tv, 0);
    const float inv = 1.0f / tr;
    const float sc  = sqrtf(tr);

    Mat Wm, Ym, Zm;                       // Wm holds A until step 1

    // ---- build A (Wm) and Z0 = 1.5I - 0.5A (Zm), directly in A-frag form ----
    #pragma unroll
    for (int I = 0; I < 2; ++I)
    #pragma unroll
    for (int J = 0; J < 2; ++J)
    #pragma unroll
    for (int s = 0; s < 2; ++s) {
        const float* bp = xg + (32 * I + m) * 64 + 32 * J + 16 * s + 8 * h;
        const float4 u0 = *(const float4*)bp;
        const float4 u1 = *(const float4*)(bp + 4);
        const float av[8] = { u0.x * inv, u0.y * inv, u0.z * inv, u0.w * inv,
                              u1.x * inv, u1.y * inv, u1.z * inv, u1.w * inv };
        float zv[8];
        #pragma unroll
        for (int i = 0; i < 8; ++i)
            zv[i] = fmaf(-0.5f, av[i], (I == J && m == 16 * s + 8 * h + i) ? 1.5f : 0.0f);
        FR ah, al, zh, zl;
        #pragma unroll
        for (int p = 0; p < 4; ++p) {
            ah.d[p] = cvt_pk_bf16(av[2*p], av[2*p+1]);
            al.d[p] = cvt_pk_bf16(av[2*p]   - __uint_as_float(ah.d[p] << 16),
                                  av[2*p+1] - __uint_as_float(ah.d[p] & 0xffff0000u));
            zh.d[p] = cvt_pk_bf16(zv[2*p], zv[2*p+1]);
            zl.d[p] = cvt_pk_bf16(zv[2*p]   - __uint_as_float(zh.d[p] << 16),
                                  zv[2*p+1] - __uint_as_float(zh.d[p] & 0xffff0000u));
        }
        Wm.h[2*I+J][s] = ah.v;  Wm.l[2*I+J][s] = al.v;
        Zm.h[2*I+J][s] = zh.v;  Zm.l[2*I+J][s] = zl.v;
    }

    // ---- C[I][J] = sum_K L[I][K] @ R[K][J], hi/lo 3-term (12 MFMA) ----
    auto mmblk = [&](const Mat& L, const Mat& R, int I, int J) -> f32x16 {
        f32x16 a = {};
        #pragma unroll
        for (int K = 0; K < 2; ++K)
        #pragma unroll
        for (int s = 0; s < 2; ++s) {
            const short8 lh = L.h[2*I+K][s], ll = L.l[2*I+K][s];
            const short8 rh = R.h[2*J+K][s], rl = R.l[2*J+K][s];   // B-op via symmetry
            a = MFMA(lh, rh, a);
            a = MFMA(lh, rl, a);
            a = MFMA(ll, rh, a);
        }
        return a;
    };

    // ---- C-layout acc of block (I,J) -> A-form frags of block (J,I) ----
    auto conv4 = [&](const f32x16& acc, int I, int J, bool wfold,
                     short8& hs0, short8& hs1, short8& ls0, short8& ls1) {
        unsigned int D01[4], D23[4], L01[4], L23[4];
        #pragma unroll
        for (int g = 0; g < 4; ++g) {
            float v0 = acc[4*g+0], v1 = acc[4*g+1], v2 = acc[4*g+2], v3 = acc[4*g+3];
            if (wfold) {   // W = 1.5I - 0.5*T
                v0 = fmaf(-0.5f, v0, (I == J && 8*g + 4*h + 0 == m) ? 1.5f : 0.0f);
                v1 = fmaf(-0.5f, v1, (I == J && 8*g + 4*h + 1 == m) ? 1.5f : 0.0f);
                v2 = fmaf(-0.5f, v2, (I == J && 8*g + 4*h + 2 == m) ? 1.5f : 0.0f);
                v3 = fmaf(-0.5f, v3, (I == J && 8*g + 4*h + 3 == m) ? 1.5f : 0.0f);
            }
            D01[g] = cvt_pk_bf16(v0, v1);
            D23[g] = cvt_pk_bf16(v2, v3);
            L01[g] = cvt_pk_bf16(v0 - __uint_as_float(D01[g] << 16),
                                 v1 - __uint_as_float(D01[g] & 0xffff0000u));
            L23[g] = cvt_pk_bf16(v2 - __uint_as_float(D23[g] << 16),
                                 v3 - __uint_as_float(D23[g] & 0xffff0000u));
        }
        SWAP_HALVES(D01[0], D01[1]); SWAP_HALVES(D23[0], D23[1]);
        SWAP_HALVES(D01[2], D01[3]); SWAP_HALVES(D23[2], D23[3]);
        SWAP_HALVES(L01[0], L01[1]); SWAP_HALVES(L23[0], L23[1]);
        SWAP_HALVES(L01[2], L01[3]); SWAP_HALVES(L23[2], L23[3]);
        FR f;
        f.d[0]=D01[0]; f.d[1]=D23[0]; f.d[2]=D01[1]; f.d[3]=D23[1]; hs0 = f.v;
        f.d[0]=D01[2]; f.d[1]=D23[2]; f.d[2]=D01[3]; f.d[3]=D23[3]; hs1 = f.v;
        f.d[0]=L01[0]; f.d[1]=L23[0]; f.d[2]=L01[1]; f.d[3]=L23[1]; ls0 = f.v;
        f.d[0]=L01[2]; f.d[1]=L23[2]; f.d[2]=L01[3]; f.d[3]=L23[3]; ls1 = f.v;
    };

    auto conv_store = [&](const f32x16& acc, Mat& D, int I, int J, bool wfold) {
        short8 a, b, c, d;
        conv4(acc, I, J, wfold, a, b, c, d);
        D.h[2*J+I][0] = a; D.h[2*J+I][1] = b;
        D.l[2*J+I][0] = c; D.l[2*J+I][1] = d;
    };

    auto conv_stage = [&](const f32x16& acc, int I, int J) {
        short8 a, b, c, d;
        conv4(acc, I, J, false, a, b, c, d);
        U4 u;
        u.v = a; stg[wv][2*J+I][0][lane] = u.u;
        u.v = b; stg[wv][2*J+I][1][lane] = u.u;
        u.v = c; stg[wv][2*J+I][2][lane] = u.u;
        u.v = d; stg[wv][2*J+I][3][lane] = u.u;
    };

    auto out_block = [&](const f32x16& acc, int I, int J) {
        float o[16];
        #pragma unroll
        for (int s = 0; s < 2; ++s)
        #pragma unroll
        for (int q = 0; q < 4; ++q) {
            float a = acc[8*s + q] * sc;        // g = 2s
            float b = acc[8*s + 4 + q] * sc;    // g = 2s+1
            SWAP_HALVES(a, b);
            o[8*s + q] = a;
            o[8*s + 4 + q] = b;
        }
        float* ob = og + (32 * J + m) * 64 + 32 * I;
        #pragma unroll
        for (int s = 0; s < 2; ++s) {
            *(float4*)(ob + 16*s + 8*h)     = make_float4(o[8*s+0], o[8*s+1], o[8*s+2], o[8*s+3]);
            *(float4*)(ob + 16*s + 8*h + 4) = make_float4(o[8*s+4], o[8*s+5], o[8*s+6], o[8*s+7]);
        }
    };

    // ---- step 1: Y1 = A @ Z0 ----
    if (iterN < 2) {
        #pragma unroll
        for (int I = 0; I < 2; ++I)
        #pragma unroll
        for (int J = 0; J < 2; ++J)
            out_block(mmblk(Wm, Zm, I, J), I, J);
        return;
    }
    #pragma unroll
    for (int I = 0; I < 2; ++I)
    #pragma unroll
    for (int J = 0; J < 2; ++J)
        conv_store(mmblk(Wm, Zm, I, J), Ym, I, J, false);

    // ---- loop ----
    for (int it = 1; it < iterN - 1; ++it) {
        // W = 1.5I - 0.5 * Z@Y
        #pragma unroll
        for (int I = 0; I < 2; ++I)
        #pragma unroll
        for (int J = 0; J < 2; ++J)
            conv_store(mmblk(Zm, Ym, I, J), Wm, I, J, true);
        // nY = Y@W  -> LDS stage (Y still an operand)
        #pragma unroll
        for (int I = 0; I < 2; ++I)
        #pragma unroll
        for (int J = 0; J < 2; ++J)
            conv_stage(mmblk(Ym, Wm, I, J), I, J);
        // nZ = W@Z : all 4 accs first, then overwrite Z (Y regs dead here)
        f32x16 z00 = mmblk(Wm, Zm, 0, 0);
        f32x16 z01 = mmblk(Wm, Zm, 0, 1);
        f32x16 z10 = mmblk(Wm, Zm, 1, 0);
        f32x16 z11 = mmblk(Wm, Zm, 1, 1);
        conv_store(z00, Zm, 0, 0, false);
        conv_store(z01, Zm, 0, 1, false);
        conv_store(z10, Zm, 1, 0, false);
        conv_store(z11, Zm, 1, 1, false);
        // reload Y (same-wave LDS, in-order)
        #pragma unroll
        for (int blk = 0; blk < 4; ++blk) {
            U4 u;
            u.u = stg[wv][blk][0][lane]; Ym.h[blk][0] = u.v;
            u.u = stg[wv][blk][1][lane]; Ym.h[blk][1] = u.v;
            u.u = stg[wv][blk][2][lane]; Ym.l[blk][0] = u.v;
            u.u = stg[wv][blk][3][lane]; Ym.l[blk][1] = u.v;
        }
    }

    // ---- final: P = 1.5I - 0.5*Z@Y ; out = (Y@P) * sc ----
    #pragma unroll
    for (int I = 0; I < 2; ++I)
    #pragma unroll
    for (int J = 0; J < 2; ++J)
        conv_store(mmblk(Zm, Ym, I, J), Wm, I, J, true);
    #pragma unroll
    for (int I = 0; I < 2; ++I)
    #pragma unroll
    for (int J = 0; J < 2; ++J)
        out_block(mmblk(Ym, Wm, I, J), I, J);
}

extern "C" void kernel_launch(void* const* d_in, const int* in_sizes, int n_in,
                              void* d_out, int out_size, void* d_ws, size_t ws_size,
                              hipStream_t stream) {
    const float* x = (const float*)d_in[0];
    const int* iterN = (const int*)d_in[1];
    float* out = (float*)d_out;
    const int B = in_sizes[0] / (64 * 64);     // 8192
    isqrtm_kernel<<<dim3(B / 4), dim3(256), 0, stream>>>(x, iterN, out);
}

// Round 8
// 351.099 us; speedup vs baseline: 1.1291x; 1.1291x over previous
//
#include <hip/hip_runtime.h>

typedef __attribute__((ext_vector_type(8))) short short8;
typedef __attribute__((ext_vector_type(16))) float f32x16;

#define MFMA(a, b, c) __builtin_amdgcn_mfma_f32_32x32x16_bf16((a), (b), (c), 0, 0, 0)

// packed f32 -> 2x bf16 (RNE), D[15:0]=bf16(a), D[31:16]=bf16(b)
__device__ __forceinline__ unsigned int cvt_pk_bf16(float a, float b) {
    unsigned int r;
    asm("v_cvt_pk_bf16_f32 %0, %1, %2" : "=v"(r) : "v"(a), "v"(b));
    return r;
}

// v_permlane32_swap_b32 a, b :  a' = {a[0:31], b[0:31]},  b' = {a[32:63], b[32:63]}
#define SWAP_HALVES(a, b) asm("v_permlane32_swap_b32 %0, %1" : "+v"(a), "+v"(b))

union FR { short8 v; unsigned int d[4]; };
union U4 { short8 v; uint4 u; };

// One 64x64 symmetric matrix, bf16 hi/lo, in MFMA A-fragment form.
// h[2*I+J][s] = A-frag of 32x32 block (I,J), K-step s. 64 VGPR total.
// B-operand of block [K][J] == A-form of block [J][K] (matrix symmetry).
struct Mat { short8 h[4][2]; short8 l[4][2]; };

// 1 wave = 1 matrix, no __syncthreads. launch_bounds(256,1): let the
// allocator take ~240-290 VGPR (3 Mats = 192 + accs/temps) WITHOUT spilling;
// round 7's (256,2) forced a 256-reg cap -> 700 MB/launch scratch traffic.
extern "C" __global__ void __launch_bounds__(256, 1)
isqrtm_kernel(const float* __restrict__ x, const int* __restrict__ iterN_p,
              float* __restrict__ out)
{
    __shared__ uint4 stg[4][4][4][64];   // [wave][dst-blk][frag][lane] = 64 KiB

    const int t = threadIdx.x;
    const int wv = t >> 6, lane = t & 63;
    const int m = lane & 31, h = lane >> 5;

    const int iterN = iterN_p[0];
    const size_t mat = (size_t)blockIdx.x * 4 + wv;
    const float* xg = x + mat * 4096;
    float* og = out + mat * 4096;

    // ---- trace (normA) ----
    float tv = xg[lane * 65];
    #pragma unroll
    for (int off = 32; off > 0; off >>= 1) tv += __shfl_down(tv, off);
    const float tr  = __shfl(tv, 0);
    const float inv = 1.0f / tr;
    const float sc  = sqrtf(tr);

    Mat Wm, Ym, Zm;                       // Wm holds A until step 1

    // ---- build A (Wm) and Z0 = 1.5I - 0.5A (Zm), directly in A-frag form ----
    #pragma unroll
    for (int I = 0; I < 2; ++I)
    #pragma unroll
    for (int J = 0; J < 2; ++J)
    #pragma unroll
    for (int s = 0; s < 2; ++s) {
        const float* bp = xg + (32 * I + m) * 64 + 32 * J + 16 * s + 8 * h;
        const float4 u0 = *(const float4*)bp;
        const float4 u1 = *(const float4*)(bp + 4);
        const float av[8] = { u0.x * inv, u0.y * inv, u0.z * inv, u0.w * inv,
                              u1.x * inv, u1.y * inv, u1.z * inv, u1.w * inv };
        float zv[8];
        #pragma unroll
        for (int i = 0; i < 8; ++i)
            zv[i] = fmaf(-0.5f, av[i], (I == J && m == 16 * s + 8 * h + i) ? 1.5f : 0.0f);
        FR ah, al, zh, zl;
        #pragma unroll
        for (int p = 0; p < 4; ++p) {
            ah.d[p] = cvt_pk_bf16(av[2*p], av[2*p+1]);
            al.d[p] = cvt_pk_bf16(av[2*p]   - __uint_as_float(ah.d[p] << 16),
                                  av[2*p+1] - __uint_as_float(ah.d[p] & 0xffff0000u));
            zh.d[p] = cvt_pk_bf16(zv[2*p], zv[2*p+1]);
            zl.d[p] = cvt_pk_bf16(zv[2*p]   - __uint_as_float(zh.d[p] << 16),
                                  zv[2*p+1] - __uint_as_float(zh.d[p] & 0xffff0000u));
        }
        Wm.h[2*I+J][s] = ah.v;  Wm.l[2*I+J][s] = al.v;
        Zm.h[2*I+J][s] = zh.v;  Zm.l[2*I+J][s] = zl.v;
    }

    // ---- C[I][J] = sum_K L[I][K] @ R[K][J], hi/lo 3-term (12 MFMA) ----
    auto mmblk = [&](const Mat& L, const Mat& R, int I, int J) -> f32x16 {
        f32x16 a = {};
        #pragma unroll
        for (int K = 0; K < 2; ++K)
        #pragma unroll
        for (int s = 0; s < 2; ++s) {
            const short8 lh = L.h[2*I+K][s], ll = L.l[2*I+K][s];
            const short8 rh = R.h[2*J+K][s], rl = R.l[2*J+K][s];   // B-op via symmetry
            a = MFMA(lh, rh, a);
            a = MFMA(lh, rl, a);
            a = MFMA(ll, rh, a);
        }
        return a;
    };

    // ---- C-layout acc of block (I,J) -> A-form frags of block (J,I) ----
    auto conv4 = [&](const f32x16& acc, int I, int J, bool wfold,
                     short8& hs0, short8& hs1, short8& ls0, short8& ls1) {
        unsigned int D01[4], D23[4], L01[4], L23[4];
        #pragma unroll
        for (int g = 0; g < 4; ++g) {
            float v0 = acc[4*g+0], v1 = acc[4*g+1], v2 = acc[4*g+2], v3 = acc[4*g+3];
            if (wfold) {   // W = 1.5I - 0.5*T
                v0 = fmaf(-0.5f, v0, (I == J && 8*g + 4*h + 0 == m) ? 1.5f : 0.0f);
                v1 = fmaf(-0.5f, v1, (I == J && 8*g + 4*h + 1 == m) ? 1.5f : 0.0f);
                v2 = fmaf(-0.5f, v2, (I == J && 8*g + 4*h + 2 == m) ? 1.5f : 0.0f);
                v3 = fmaf(-0.5f, v3, (I == J && 8*g + 4*h + 3 == m) ? 1.5f : 0.0f);
            }
            D01[g] = cvt_pk_bf16(v0, v1);
            D23[g] = cvt_pk_bf16(v2, v3);
            L01[g] = cvt_pk_bf16(v0 - __uint_as_float(D01[g] << 16),
                                 v1 - __uint_as_float(D01[g] & 0xffff0000u));
            L23[g] = cvt_pk_bf16(v2 - __uint_as_float(D23[g] << 16),
                                 v3 - __uint_as_float(D23[g] & 0xffff0000u));
        }
        SWAP_HALVES(D01[0], D01[1]); SWAP_HALVES(D23[0], D23[1]);
        SWAP_HALVES(D01[2], D01[3]); SWAP_HALVES(D23[2], D23[3]);
        SWAP_HALVES(L01[0], L01[1]); SWAP_HALVES(L23[0], L23[1]);
        SWAP_HALVES(L01[2], L01[3]); SWAP_HALVES(L23[2], L23[3]);
        FR f;
        f.d[0]=D01[0]; f.d[1]=D23[0]; f.d[2]=D01[1]; f.d[3]=D23[1]; hs0 = f.v;
        f.d[0]=D01[2]; f.d[1]=D23[2]; f.d[2]=D01[3]; f.d[3]=D23[3]; hs1 = f.v;
        f.d[0]=L01[0]; f.d[1]=L23[0]; f.d[2]=L01[1]; f.d[3]=L23[1]; ls0 = f.v;
        f.d[0]=L01[2]; f.d[1]=L23[2]; f.d[2]=L01[3]; f.d[3]=L23[3]; ls1 = f.v;
    };

    auto conv_store = [&](const f32x16& acc, Mat& D, int I, int J, bool wfold) {
        short8 a, b, c, d;
        conv4(acc, I, J, wfold, a, b, c, d);
        D.h[2*J+I][0] = a; D.h[2*J+I][1] = b;
        D.l[2*J+I][0] = c; D.l[2*J+I][1] = d;
    };

    auto conv_stage = [&](const f32x16& acc, int I, int J) {
        short8 a, b, c, d;
        conv4(acc, I, J, false, a, b, c, d);
        U4 u;
        u.v = a; stg[wv][2*J+I][0][lane] = u.u;
        u.v = b; stg[wv][2*J+I][1][lane] = u.u;
        u.v = c; stg[wv][2*J+I][2][lane] = u.u;
        u.v = d; stg[wv][2*J+I][3][lane] = u.u;
    };

    auto out_block = [&](const f32x16& acc, int I, int J) {
        float o[16];
        #pragma unroll
        for (int s = 0; s < 2; ++s)
        #pragma unroll
        for (int q = 0; q < 4; ++q) {
            float a = acc[8*s + q] * sc;        // g = 2s
            float b = acc[8*s + 4 + q] * sc;    // g = 2s+1
            SWAP_HALVES(a, b);
            o[8*s + q] = a;
            o[8*s + 4 + q] = b;
        }
        float* ob = og + (32 * J + m) * 64 + 32 * I;
        #pragma unroll
        for (int s = 0; s < 2; ++s) {
            *(float4*)(ob + 16*s + 8*h)     = make_float4(o[8*s+0], o[8*s+1], o[8*s+2], o[8*s+3]);
            *(float4*)(ob + 16*s + 8*h + 4) = make_float4(o[8*s+4], o[8*s+5], o[8*s+6], o[8*s+7]);
        }
    };

    // ---- step 1: Y1 = A @ Z0 ----
    if (iterN < 2) {
        #pragma unroll
        for (int I = 0; I < 2; ++I)
        #pragma unroll
        for (int J = 0; J < 2; ++J)
            out_block(mmblk(Wm, Zm, I, J), I, J);
        return;
    }
    #pragma unroll
    for (int I = 0; I < 2; ++I)
    #pragma unroll
    for (int J = 0; J < 2; ++J)
        conv_store(mmblk(Wm, Zm, I, J), Ym, I, J, false);

    // ---- loop ----
    for (int it = 1; it < iterN - 1; ++it) {
        // W = 1.5I - 0.5 * Z@Y
        #pragma unroll
        for (int I = 0; I < 2; ++I)
        #pragma unroll
        for (int J = 0; J < 2; ++J)
            conv_store(mmblk(Zm, Ym, I, J), Wm, I, J, true);
        // nY = Y@W  -> LDS stage (Y still an operand)
        #pragma unroll
        for (int I = 0; I < 2; ++I)
        #pragma unroll
        for (int J = 0; J < 2; ++J)
            conv_stage(mmblk(Ym, Wm, I, J), I, J);
        // nZ = W@Z in column pairs: outputs for column J only read Z-blocks
        // {2J, 2J+1}, so overwrite them before computing column J=1.
        // Peak live: Wm + Zm + 2 accs (vs 4 in round 7).
        {
            f32x16 z00 = mmblk(Wm, Zm, 0, 0);    // reads Z blk 0,1
            f32x16 z10 = mmblk(Wm, Zm, 1, 0);    // reads Z blk 0,1
            conv_store(z00, Zm, 0, 0, false);    // writes Z blk 0
            conv_store(z10, Zm, 1, 0, false);    // writes Z blk 1
            f32x16 z01 = mmblk(Wm, Zm, 0, 1);    // reads Z blk 2,3
            f32x16 z11 = mmblk(Wm, Zm, 1, 1);    // reads Z blk 2,3
            conv_store(z01, Zm, 0, 1, false);    // writes Z blk 2
            conv_store(z11, Zm, 1, 1, false);    // writes Z blk 3
        }
        // reload Y (same-wave LDS, in-order)
        #pragma unroll
        for (int blk = 0; blk < 4; ++blk) {
            U4 u;
            u.u = stg[wv][blk][0][lane]; Ym.h[blk][0] = u.v;
            u.u = stg[wv][blk][1][lane]; Ym.h[blk][1] = u.v;
            u.u = stg[wv][blk][2][lane]; Ym.l[blk][0] = u.v;
            u.u = stg[wv][blk][3][lane]; Ym.l[blk][1] = u.v;
        }
    }

    // ---- final: P = 1.5I - 0.5*Z@Y ; out = (Y@P) * sc ----
    #pragma unroll
    for (int I = 0; I < 2; ++I)
    #pragma unroll
    for (int J = 0; J < 2; ++J)
        conv_store(mmblk(Zm, Ym, I, J), Wm, I, J, true);
    #pragma unroll
    for (int I = 0; I < 2; ++I)
    #pragma unroll
    for (int J = 0; J < 2; ++J)
        out_block(mmblk(Ym, Wm, I, J), I, J);
}

extern "C" void kernel_launch(void* const* d_in, const int* in_sizes, int n_in,
                              void* d_out, int out_size, void* d_ws, size_t ws_size,
                              hipStream_t stream) {
    const float* x = (const float*)d_in[0];
    const int* iterN = (const int*)d_in[1];
    float* out = (float*)d_out;
    const int B = in_sizes[0] / (64 * 64);     // 8192
    isqrtm_kernel<<<dim3(B / 4), dim3(256), 0, stream>>>(x, iterN, out);
}